// Round 1
// baseline (3079.547 us; speedup 1.0000x reference)
//
#include <hip/hip_runtime.h>

#define NB 64
#define NT 4096
#define ND 32
#define NH 128
#define CHUNK 128
#define NCHUNK (NT / CHUNK)

typedef _Float16 half8 __attribute__((ext_vector_type(8)));
typedef float floatx4 __attribute__((ext_vector_type(4)));

__device__ __forceinline__ float sigmoidf_fast(float x) {
    return __builtin_amdgcn_rcpf(1.0f + __expf(-x));
}
__device__ __forceinline__ float tanhf_fast(float x) {
    // 1 - 2/(1+exp(2x)); exp overflow -> inf -> rcp -> 0 -> +1; underflow -> -1. Stable.
    return 1.0f - 2.0f * __builtin_amdgcn_rcpf(1.0f + __expf(2.0f * x));
}
__device__ __forceinline__ unsigned short f2h_bits(float x) {
    _Float16 h = (_Float16)x;
    return __builtin_bit_cast(unsigned short, h);
}

// One workgroup per batch sample. 8 waves; wave w owns hidden rows [16w, 16w+16).
// Per step: gates_pre = [W_hh | W_ih] . [h ; u_t] via f16 MFMA 16x16x32,
// weights resident in VGPRs as A-fragments, h/u broadcast across all 16 B-columns.
__global__ void __launch_bounds__(512, 2) gru_fused_kernel(
    const float* __restrict__ u,
    const float* __restrict__ w_ih,
    const float* __restrict__ w_hh,
    const float* __restrict__ b_ih,
    const float* __restrict__ b_hh,
    const float* __restrict__ fc_w,
    const float* __restrict__ fc_b,
    float* __restrict__ out)
{
    __shared__ float u_lds[CHUNK * ND];                   // 16 KB staged input chunk
    __shared__ __align__(16) unsigned short hbuf[2][NH];  // fp16 hidden state ping-pong
    __shared__ float parts[2][8];                         // fc partial sums per wave

    const int tid = (int)threadIdx.x;
    const int b   = (int)blockIdx.x;
    const int w   = tid >> 6;   // wave 0..7
    const int l   = tid & 63;   // lane
    const int q   = l >> 4;     // lane quad-group 0..3
    const int cl  = l & 15;     // A-row / C-col within tile
    const int jb  = w * 16;     // this wave's hidden-row base

    // ---- preload weight A-fragments (f32 -> f16). A[row=cl][k=c*32+q*8+i] ----
    half8 aR[4], aZ[4], aN[4];
    #pragma unroll
    for (int c = 0; c < 4; ++c) {
        const float* pr = w_hh + (size_t)(0 * NH + jb + cl) * NH + c * 32 + q * 8;
        const float* pz = w_hh + (size_t)(1 * NH + jb + cl) * NH + c * 32 + q * 8;
        const float* pn = w_hh + (size_t)(2 * NH + jb + cl) * NH + c * 32 + q * 8;
        #pragma unroll
        for (int i = 0; i < 8; ++i) {
            aR[c][i] = (_Float16)pr[i];
            aZ[c][i] = (_Float16)pz[i];
            aN[c][i] = (_Float16)pn[i];
        }
    }
    half8 aiR, aiZ, aiN;  // input-projection tiles, K = 32 = D
    {
        const float* pr = w_ih + (size_t)(0 * NH + jb + cl) * ND + q * 8;
        const float* pz = w_ih + (size_t)(1 * NH + jb + cl) * ND + q * 8;
        const float* pn = w_ih + (size_t)(2 * NH + jb + cl) * ND + q * 8;
        #pragma unroll
        for (int i = 0; i < 8; ++i) {
            aiR[i] = (_Float16)pr[i];
            aiZ[i] = (_Float16)pz[i];
            aiN[i] = (_Float16)pn[i];
        }
    }

    // C rows for this lane: j = jb + q*4 + i  (i = 0..3). Bias-init accumulators.
    floatx4 rb, zb, xb, hb;
    float fcw[4];
    #pragma unroll
    for (int i = 0; i < 4; ++i) {
        const int j = jb + q * 4 + i;
        rb[i] = b_ih[0 * NH + j] + b_hh[0 * NH + j];
        zb[i] = b_ih[1 * NH + j] + b_hh[1 * NH + j];
        xb[i] = b_ih[2 * NH + j];   // x-part of n kept separate (r multiplies h-part only)
        hb[i] = b_hh[2 * NH + j];
        fcw[i] = fc_w[j];
    }
    const float fcb = fc_b[0];
    float hold[4] = {0.f, 0.f, 0.f, 0.f};  // f32 master copy of this lane's h rows

    if (tid < 64) reinterpret_cast<unsigned int*>(hbuf[0])[tid] = 0u;  // h0 = 0

    const float* ubase = u + (size_t)b * NT * ND;
    float4 pre0 = *reinterpret_cast<const float4*>(ubase + (size_t)tid * 4);
    float4 pre1 = *reinterpret_cast<const float4*>(ubase + (size_t)(tid + 512) * 4);
    float* outb = out + (size_t)b * NT;

    for (int ci = 0; ci < NCHUNK; ++ci) {
        __syncthreads();  // previous chunk fully consumed (step barrier pattern guarantees reads precede this)
        reinterpret_cast<float4*>(u_lds)[tid]       = pre0;
        reinterpret_cast<float4*>(u_lds)[tid + 512] = pre1;
        if (ci + 1 < NCHUNK) {  // prefetch next chunk into registers; consumed next boundary
            const float* nb = ubase + (size_t)(ci + 1) * CHUNK * ND;
            pre0 = *reinterpret_cast<const float4*>(nb + (size_t)tid * 4);
            pre1 = *reinterpret_cast<const float4*>(nb + (size_t)(tid + 512) * 4);
        }
        __syncthreads();

        for (int tl = 0; tl < CHUNK; ++tl) {
            const int t   = ci * CHUNK + tl;
            const int cur = t & 1;
            const int nxt = cur ^ 1;

            // B-fragments: h (4 k-chunks) and u_t, broadcast to all 16 columns.
            half8 bh[4];
            #pragma unroll
            for (int c = 0; c < 4; ++c)
                bh[c] = *reinterpret_cast<const half8*>(&hbuf[cur][c * 32 + q * 8]);

            half8 bu;
            {
                const float4 ua  = *reinterpret_cast<const float4*>(&u_lds[tl * ND + q * 8]);
                const float4 ub4 = *reinterpret_cast<const float4*>(&u_lds[tl * ND + q * 8 + 4]);
                bu[0] = (_Float16)ua.x;  bu[1] = (_Float16)ua.y;
                bu[2] = (_Float16)ua.z;  bu[3] = (_Float16)ua.w;
                bu[4] = (_Float16)ub4.x; bu[5] = (_Float16)ub4.y;
                bu[6] = (_Float16)ub4.z; bu[7] = (_Float16)ub4.w;
            }

            floatx4 ar = rb, az = zb, ax = xb, ah = hb;
            ar = __builtin_amdgcn_mfma_f32_16x16x32_f16(aiR, bu, ar, 0, 0, 0);
            az = __builtin_amdgcn_mfma_f32_16x16x32_f16(aiZ, bu, az, 0, 0, 0);
            ax = __builtin_amdgcn_mfma_f32_16x16x32_f16(aiN, bu, ax, 0, 0, 0);
            #pragma unroll
            for (int c = 0; c < 4; ++c) {
                ar = __builtin_amdgcn_mfma_f32_16x16x32_f16(aR[c], bh[c], ar, 0, 0, 0);
                az = __builtin_amdgcn_mfma_f32_16x16x32_f16(aZ[c], bh[c], az, 0, 0, 0);
                ah = __builtin_amdgcn_mfma_f32_16x16x32_f16(aN[c], bh[c], ah, 0, 0, 0);
            }

            // Gate math, all lane-local in f32.
            float p = 0.f;
            unsigned short hb16[4];
            #pragma unroll
            for (int i = 0; i < 4; ++i) {
                const float r = sigmoidf_fast(ar[i]);
                const float z = sigmoidf_fast(az[i]);
                const float n = tanhf_fast(ax[i] + r * ah[i]);
                const float h = (1.f - z) * n + z * hold[i];
                hold[i] = h;
                p += fcw[i] * h;
                hb16[i] = f2h_bits(h);
            }
            // fc partial: sum across the 4 q-groups (lanes l^{16,32,48})
            p += __shfl_xor(p, 16);
            p += __shfl_xor(p, 32);

            if (cl == 0) {  // one writer per 4 hidden rows (cols are redundant copies)
                uint2 v;
                v.x = (unsigned int)hb16[0] | ((unsigned int)hb16[1] << 16);
                v.y = (unsigned int)hb16[2] | ((unsigned int)hb16[3] << 16);
                *reinterpret_cast<uint2*>(&hbuf[nxt][jb + q * 4]) = v;
            }
            if (l == 0) parts[cur][w] = p;
            __syncthreads();
            if (tid == 0) {
                float s = fcb;
                #pragma unroll
                for (int k = 0; k < 8; ++k) s += parts[cur][k];
                outb[t] = s;
            }
        }
    }
}

extern "C" void kernel_launch(void* const* d_in, const int* in_sizes, int n_in,
                              void* d_out, int out_size, void* d_ws, size_t ws_size,
                              hipStream_t stream)
{
    const float* u    = (const float*)d_in[0];
    const float* w_ih = (const float*)d_in[1];
    const float* w_hh = (const float*)d_in[2];
    const float* b_ih = (const float*)d_in[3];
    const float* b_hh = (const float*)d_in[4];
    const float* fc_w = (const float*)d_in[5];
    const float* fc_b = (const float*)d_in[6];

    gru_fused_kernel<<<dim3(NB), dim3(512), 0, stream>>>(
        u, w_ih, w_hh, b_ih, b_hh, fc_w, fc_b, (float*)d_out);
}

// Round 2
// 2301.280 us; speedup vs baseline: 1.3382x; 1.3382x over previous
//
#include <hip/hip_runtime.h>

#define NB 64
#define NT 4096
#define ND 32
#define NH 128
#define CHUNK 128
#define NCHUNK (NT / CHUNK)

typedef _Float16 half8 __attribute__((ext_vector_type(8)));
typedef float floatx4 __attribute__((ext_vector_type(4)));

__device__ __forceinline__ float sigmoidf_fast(float x) {
    return __builtin_amdgcn_rcpf(1.0f + __expf(-x));
}
__device__ __forceinline__ float tanhf_fast(float x) {
    // 1 - 2/(1+exp(2x)); overflow -> +1, underflow -> -1. Stable.
    return 1.0f - 2.0f * __builtin_amdgcn_rcpf(1.0f + __expf(2.0f * x));
}
__device__ __forceinline__ unsigned short f2h_bits(float x) {
    _Float16 h = (_Float16)x;
    return __builtin_bit_cast(unsigned short, h);
}
// constant-indexed 4:1 mux (avoids runtime-indexed ext_vector -> scratch, rule #20)
__device__ __forceinline__ float sel4(floatx4 v, bool b0, bool b1) {
    float s0 = b0 ? v[1] : v[0];
    float s1 = b0 ? v[3] : v[2];
    return b1 ? s1 : s0;
}

// One workgroup per batch sample. 8 waves; wave w owns hidden rows [16w, 16w+16).
// Per step: hh-gates via f16 MFMA 16x16x32 (weights resident in VGPRs, h broadcast
// across the 16 B-columns). Input projections are software-pipelined one step
// ahead (independent of h). Gate VALU deduped: lane handles only unit cl&3.
__global__ void __launch_bounds__(512, 2) gru_fused_kernel(
    const float* __restrict__ u,
    const float* __restrict__ w_ih,
    const float* __restrict__ w_hh,
    const float* __restrict__ b_ih,
    const float* __restrict__ b_hh,
    const float* __restrict__ fc_w,
    const float* __restrict__ fc_b,
    float* __restrict__ out)
{
    __shared__ _Float16 u16[CHUNK * ND];                  // 8 KB f16 staged input chunk
    __shared__ __align__(16) unsigned short hbuf[2][NH];  // fp16 hidden state ping-pong
    __shared__ float pbuf[CHUNK][8];                      // per-step per-wave fc partials

    const int tid = (int)threadIdx.x;
    const int b   = (int)blockIdx.x;
    const int w   = tid >> 6;   // wave 0..7
    const int l   = tid & 63;   // lane
    const int q   = l >> 4;     // lane quad-group 0..3
    const int cl  = l & 15;     // A-row / C-col within tile
    const int jb  = w * 16;     // this wave's hidden-row base
    const bool s0 = (cl & 1) != 0;   // gate-unit select bits (unit = cl&3)
    const bool s1 = (cl & 2) != 0;

    // ---- preload weight A-fragments (f32 -> f16). A[row=cl][k=c*32+q*8+i] ----
    half8 aR[4], aZ[4], aN[4];
    #pragma unroll
    for (int c = 0; c < 4; ++c) {
        const float* pr = w_hh + (size_t)(0 * NH + jb + cl) * NH + c * 32 + q * 8;
        const float* pz = w_hh + (size_t)(1 * NH + jb + cl) * NH + c * 32 + q * 8;
        const float* pn = w_hh + (size_t)(2 * NH + jb + cl) * NH + c * 32 + q * 8;
        #pragma unroll
        for (int i = 0; i < 8; ++i) {
            aR[c][i] = (_Float16)pr[i];
            aZ[c][i] = (_Float16)pz[i];
            aN[c][i] = (_Float16)pn[i];
        }
    }
    half8 aiR, aiZ, aiN;  // input-projection tiles, K = 32 = D
    {
        const float* pr = w_ih + (size_t)(0 * NH + jb + cl) * ND + q * 8;
        const float* pz = w_ih + (size_t)(1 * NH + jb + cl) * ND + q * 8;
        const float* pn = w_ih + (size_t)(2 * NH + jb + cl) * ND + q * 8;
        #pragma unroll
        for (int i = 0; i < 8; ++i) {
            aiR[i] = (_Float16)pr[i];
            aiZ[i] = (_Float16)pz[i];
            aiN[i] = (_Float16)pn[i];
        }
    }

    // Bias-init accumulator vectors (C rows j = jb + q*4 + i).
    floatx4 rbv, zbv, xbv, hbv;
    #pragma unroll
    for (int i = 0; i < 4; ++i) {
        const int j = jb + q * 4 + i;
        rbv[i] = b_ih[0 * NH + j] + b_hh[0 * NH + j];
        zbv[i] = b_ih[1 * NH + j] + b_hh[1 * NH + j];
        xbv[i] = b_ih[2 * NH + j];   // x-part of n (r multiplies the h-part only)
        hbv[i] = b_hh[2 * NH + j];
    }
    const int   jmine = jb + q * 4 + (cl & 3);  // the one row this lane's gate unit owns
    const float fcwv  = fc_w[jmine];
    const float fcb   = fc_b[0];
    float hold = 0.f;                           // f32 master copy of this lane's h row

    if (tid < 64) reinterpret_cast<unsigned int*>(hbuf[0])[tid] = 0u;  // h0 = 0

    const float* ubase = u + (size_t)b * NT * ND;
    float*       outb  = out + (size_t)b * NT;
    const floatx4 zero4 = {0.f, 0.f, 0.f, 0.f};

    // prefetch chunk 0 into registers (8 floats / thread)
    float4 pre0 = *reinterpret_cast<const float4*>(ubase + (size_t)tid * 8);
    float4 pre1 = *reinterpret_cast<const float4*>(ubase + (size_t)tid * 8 + 4);

    floatx4 xr_c, xz_c, xn_c;  // pipelined input-proj accumulators for current step

    for (int ci = 0; ci < NCHUNK; ++ci) {
        // ---- stage current chunk (f32 -> f16), prefetch next, flush prev outputs ----
        {
            half8 hv;
            hv[0] = (_Float16)pre0.x; hv[1] = (_Float16)pre0.y;
            hv[2] = (_Float16)pre0.z; hv[3] = (_Float16)pre0.w;
            hv[4] = (_Float16)pre1.x; hv[5] = (_Float16)pre1.y;
            hv[6] = (_Float16)pre1.z; hv[7] = (_Float16)pre1.w;
            *reinterpret_cast<half8*>(&u16[tid * 8]) = hv;
        }
        if (ci + 1 < NCHUNK) {
            const float* nb2 = ubase + (size_t)(ci + 1) * CHUNK * ND;
            pre0 = *reinterpret_cast<const float4*>(nb2 + (size_t)tid * 8);
            pre1 = *reinterpret_cast<const float4*>(nb2 + (size_t)tid * 8 + 4);
        }
        if (ci > 0 && tid < CHUNK) {  // flush previous chunk's fc outputs
            float s = fcb;
            #pragma unroll
            for (int k = 0; k < 8; ++k) s += pbuf[tid][k];
            outb[(ci - 1) * CHUNK + tid] = s;
        }
        __syncthreads();

        // input projection for tl = 0 (reads freshly staged u16)
        {
            half8 bu = *reinterpret_cast<const half8*>(&u16[0 * ND + q * 8]);
            xr_c = rbv; xz_c = zbv; xn_c = xbv;
            xr_c = __builtin_amdgcn_mfma_f32_16x16x32_f16(aiR, bu, xr_c, 0, 0, 0);
            xz_c = __builtin_amdgcn_mfma_f32_16x16x32_f16(aiZ, bu, xz_c, 0, 0, 0);
            xn_c = __builtin_amdgcn_mfma_f32_16x16x32_f16(aiN, bu, xn_c, 0, 0, 0);
        }

        for (int tl = 0; tl < CHUNK; ++tl) {
            const int cur = tl & 1;      // CHUNK even -> parity consistent across chunks
            const int nxt = cur ^ 1;

            // h B-fragments (same addr across the 16 cl lanes -> LDS broadcast, free)
            half8 bh0 = *reinterpret_cast<const half8*>(&hbuf[cur][0 * 32 + q * 8]);
            half8 bh1 = *reinterpret_cast<const half8*>(&hbuf[cur][1 * 32 + q * 8]);
            half8 bh2 = *reinterpret_cast<const half8*>(&hbuf[cur][2 * 32 + q * 8]);
            half8 bh3 = *reinterpret_cast<const half8*>(&hbuf[cur][3 * 32 + q * 8]);

            // hh projections: two 2-deep chains per gate (K split) -> shorter dep chain
            floatx4 ra = xr_c, za = xz_c, ha = hbv;
            floatx4 rb2 = zero4, zb2 = zero4, hb2 = zero4;
            ra  = __builtin_amdgcn_mfma_f32_16x16x32_f16(aR[0], bh0, ra,  0, 0, 0);
            za  = __builtin_amdgcn_mfma_f32_16x16x32_f16(aZ[0], bh0, za,  0, 0, 0);
            ha  = __builtin_amdgcn_mfma_f32_16x16x32_f16(aN[0], bh0, ha,  0, 0, 0);
            rb2 = __builtin_amdgcn_mfma_f32_16x16x32_f16(aR[2], bh2, rb2, 0, 0, 0);
            zb2 = __builtin_amdgcn_mfma_f32_16x16x32_f16(aZ[2], bh2, zb2, 0, 0, 0);
            hb2 = __builtin_amdgcn_mfma_f32_16x16x32_f16(aN[2], bh2, hb2, 0, 0, 0);
            ra  = __builtin_amdgcn_mfma_f32_16x16x32_f16(aR[1], bh1, ra,  0, 0, 0);
            za  = __builtin_amdgcn_mfma_f32_16x16x32_f16(aZ[1], bh1, za,  0, 0, 0);
            ha  = __builtin_amdgcn_mfma_f32_16x16x32_f16(aN[1], bh1, ha,  0, 0, 0);
            rb2 = __builtin_amdgcn_mfma_f32_16x16x32_f16(aR[3], bh3, rb2, 0, 0, 0);
            zb2 = __builtin_amdgcn_mfma_f32_16x16x32_f16(aZ[3], bh3, zb2, 0, 0, 0);
            hb2 = __builtin_amdgcn_mfma_f32_16x16x32_f16(aN[3], bh3, hb2, 0, 0, 0);

            const float pre_x = sel4(xn_c, s0, s1);  // capture before xn_c is recycled

            // software-pipeline next step's input projection (off the h critical path)
            if (tl + 1 < CHUNK) {
                half8 bu = *reinterpret_cast<const half8*>(&u16[(tl + 1) * ND + q * 8]);
                xr_c = rbv; xz_c = zbv; xn_c = xbv;
                xr_c = __builtin_amdgcn_mfma_f32_16x16x32_f16(aiR, bu, xr_c, 0, 0, 0);
                xz_c = __builtin_amdgcn_mfma_f32_16x16x32_f16(aiZ, bu, xz_c, 0, 0, 0);
                xn_c = __builtin_amdgcn_mfma_f32_16x16x32_f16(aiN, bu, xn_c, 0, 0, 0);
            }

            // gate math: this lane handles only unit (cl&3) -> 1 unit instead of 4
            const float pre_r = sel4(ra, s0, s1) + sel4(rb2, s0, s1);
            const float pre_z = sel4(za, s0, s1) + sel4(zb2, s0, s1);
            const float pre_h = sel4(ha, s0, s1) + sel4(hb2, s0, s1);
            const float rg = sigmoidf_fast(pre_r);
            const float zg = sigmoidf_fast(pre_z);
            const float ng = tanhf_fast(pre_x + rg * pre_h);
            const float h  = ng + zg * (hold - ng);
            hold = h;

            // fc partial: rows are spread over (q, cl&3); quartet sums are redundant
            float p = fcwv * h;
            p += __shfl_xor(p, 1);
            p += __shfl_xor(p, 2);
            p += __shfl_xor(p, 16);
            p += __shfl_xor(p, 32);
            if (l == 0) pbuf[tl][w] = p;

            if (cl < 4) hbuf[nxt][jb + q * 4 + cl] = f2h_bits(h);  // one writer per row
            __syncthreads();
        }
    }

    // final flush (after last step's barrier)
    if (tid < CHUNK) {
        float s = fcb;
        #pragma unroll
        for (int k = 0; k < 8; ++k) s += pbuf[tid][k];
        outb[(NCHUNK - 1) * CHUNK + tid] = s;
    }
}

extern "C" void kernel_launch(void* const* d_in, const int* in_sizes, int n_in,
                              void* d_out, int out_size, void* d_ws, size_t ws_size,
                              hipStream_t stream)
{
    const float* u    = (const float*)d_in[0];
    const float* w_ih = (const float*)d_in[1];
    const float* w_hh = (const float*)d_in[2];
    const float* b_ih = (const float*)d_in[3];
    const float* b_hh = (const float*)d_in[4];
    const float* fc_w = (const float*)d_in[5];
    const float* fc_b = (const float*)d_in[6];

    gru_fused_kernel<<<dim3(NB), dim3(512), 0, stream>>>(
        u, w_ih, w_hh, b_ih, b_hh, fc_w, fc_b, (float*)d_out);
}

// Round 3
// 1547.349 us; speedup vs baseline: 1.9902x; 1.4872x over previous
//
#include <hip/hip_runtime.h>

#define NB 64
#define NT 4096
#define ND 32
#define NH 128
#define SC 32                    // steps per sub-chunk
#define NSC (NT / SC)            // 128 sub-chunks
#define XGS (3 * NH + 4)         // 388: padded xg row stride (f32), 388%32=4 -> no bank clash

typedef _Float16 half8 __attribute__((ext_vector_type(8)));
typedef float floatx4 __attribute__((ext_vector_type(4)));

// s_barrier WITHOUT vmcnt drain: orders LDS only (all cross-wave data is LDS).
// Lets u-prefetch global loads stay in flight across step barriers.
__device__ __forceinline__ void wg_barrier() {
    asm volatile("s_waitcnt lgkmcnt(0)\n\ts_barrier" ::: "memory");
}

// constant-indexed 4:1 mux (avoids runtime-indexed ext_vector -> scratch)
__device__ __forceinline__ float sel4(floatx4 v, bool b0, bool b1) {
    float s0 = b0 ? v[1] : v[0];
    float s1 = b0 ? v[3] : v[2];
    return b1 ? s1 : s0;
}

// One workgroup per batch sample. 8 waves; wave w owns hidden rows [16w,16w+16).
// Steady-state step: ds_read h + xg quads -> 12 MFMA (3 gates x 4-deep, K=128)
// -> per-lane gate unit (cl&3) -> ds_write h -> barrier. fc + input projections
// are batched per 32-step sub-chunk, off the recurrent critical path.
// Weights prescaled: r/z by -log2e (sigmoid = rcp(1+exp2(s))),
//                    n   by 2*log2e (tanh = 1-2*rcp(1+exp2(s))).
__global__ void __launch_bounds__(512, 2) gru_fused_kernel(
    const float* __restrict__ u,
    const float* __restrict__ w_ih,
    const float* __restrict__ w_hh,
    const float* __restrict__ b_ih,
    const float* __restrict__ b_hh,
    const float* __restrict__ fc_w,
    const float* __restrict__ fc_b,
    float* __restrict__ out)
{
    __shared__ float    xg_lds[SC * XGS];                     // 48.5 KB gate pre-activations (biased, prescaled)
    __shared__ __align__(16) _Float16 hhist[(SC + 1) * NH];   // 8.25 KB h history (slot 0 = carry-in)
    __shared__ __align__(16) _Float16 u16[SC * ND];           // 2 KB f16 input sub-chunk
    __shared__ float    fcw_lds[NH];                          // 0.5 KB

    const int tid = (int)threadIdx.x;
    const int b   = (int)blockIdx.x;
    const int w   = tid >> 6;   // wave 0..7
    const int l   = tid & 63;   // lane
    const int q   = l >> 4;     // lane quad-group 0..3
    const int cl  = l & 15;     // A-row / B-col / C-col within tile
    const int jb  = w * 16;     // this wave's hidden-row base
    const bool s0 = (cl & 1) != 0;   // gate-unit select (unit = cl&3)
    const bool s1 = (cl & 2) != 0;

    const float dsc = -1.44269504089f;  // -log2(e)
    const float csc =  2.88539008178f;  // 2*log2(e)

    // ---- weight A-fragments, prescaled (A[row=cl][k=c*32+q*8+i]) ----
    half8 aR[4], aZ[4], aN[4];
    #pragma unroll
    for (int c = 0; c < 4; ++c) {
        const float* pr = w_hh + (size_t)(0 * NH + jb + cl) * NH + c * 32 + q * 8;
        const float* pz = w_hh + (size_t)(1 * NH + jb + cl) * NH + c * 32 + q * 8;
        const float* pn = w_hh + (size_t)(2 * NH + jb + cl) * NH + c * 32 + q * 8;
        #pragma unroll
        for (int i = 0; i < 8; ++i) {
            aR[c][i] = (_Float16)(dsc * pr[i]);
            aZ[c][i] = (_Float16)(dsc * pz[i]);
            aN[c][i] = (_Float16)(csc * pn[i]);
        }
    }
    half8 aiR, aiZ, aiN;  // input-projection tiles, K = 32 = D
    {
        const float* pr = w_ih + (size_t)(0 * NH + jb + cl) * ND + q * 8;
        const float* pz = w_ih + (size_t)(1 * NH + jb + cl) * ND + q * 8;
        const float* pn = w_ih + (size_t)(2 * NH + jb + cl) * ND + q * 8;
        #pragma unroll
        for (int i = 0; i < 8; ++i) {
            aiR[i] = (_Float16)(dsc * pr[i]);
            aiZ[i] = (_Float16)(dsc * pz[i]);
            aiN[i] = (_Float16)(csc * pn[i]);
        }
    }

    // Prescaled bias quads (C rows j = jb + q*4 + i).
    floatx4 rbv, zbv, xbv, hbv;
    #pragma unroll
    for (int i = 0; i < 4; ++i) {
        const int j = jb + q * 4 + i;
        rbv[i] = dsc * (b_ih[0 * NH + j] + b_hh[0 * NH + j]);
        zbv[i] = dsc * (b_ih[1 * NH + j] + b_hh[1 * NH + j]);
        xbv[i] = csc * b_ih[2 * NH + j];   // x-part of n (r multiplies h-part only)
        hbv[i] = csc * b_hh[2 * NH + j];
    }
    const float fcb = fc_b[0];
    float hold = 0.f;   // f32 master copy of this lane's h row (row jb+q*4+(cl&3))

    const float* ubase = u + (size_t)b * NT * ND;
    float*       outb  = out + (size_t)b * NT;

    // ---- prologue: h0 = 0, fc_w to LDS, stage u16 for s=0, prefetch s=1 ----
    if (tid < 64)  reinterpret_cast<unsigned int*>(hhist)[tid] = 0u;
    if (tid < NH)  fcw_lds[tid] = fc_w[tid];
    {
        float2 uv = *reinterpret_cast<const float2*>(ubase + 2 * tid);
        unsigned short h0b = __builtin_bit_cast(unsigned short, (_Float16)uv.x);
        unsigned short h1b = __builtin_bit_cast(unsigned short, (_Float16)uv.y);
        reinterpret_cast<unsigned int*>(u16)[tid] =
            (unsigned int)h0b | ((unsigned int)h1b << 16);
    }
    float2 upre = *reinterpret_cast<const float2*>(ubase + SC * ND + 2 * tid);
    wg_barrier();

    for (int s = 0; s < NSC; ++s) {
        if (s > 0) {
            // fc flush for sub-chunk s-1 (reads hhist[1..SC])
            if (tid < 256) {
                const int tloc = tid >> 3;
                const int part = tid & 7;
                const _Float16* hp = hhist + (tloc + 1) * NH + part * 16;
                half8 h0 = *reinterpret_cast<const half8*>(hp);
                half8 h1 = *reinterpret_cast<const half8*>(hp + 8);
                float p = 0.f;
                #pragma unroll
                for (int i = 0; i < 8; ++i) p += (float)h0[i] * fcw_lds[part * 16 + i];
                #pragma unroll
                for (int i = 0; i < 8; ++i) p += (float)h1[i] * fcw_lds[part * 16 + 8 + i];
                p += __shfl_xor(p, 1);
                p += __shfl_xor(p, 2);
                p += __shfl_xor(p, 4);
                if (part == 0) outb[(s - 1) * SC + tloc] = p + fcb;
            }
            // stage u16 for sub-chunk s (from prefetch), prefetch s+1
            {
                unsigned short h0b = __builtin_bit_cast(unsigned short, (_Float16)upre.x);
                unsigned short h1b = __builtin_bit_cast(unsigned short, (_Float16)upre.y);
                reinterpret_cast<unsigned int*>(u16)[tid] =
                    (unsigned int)h0b | ((unsigned int)h1b << 16);
            }
            if (s + 1 < NSC)
                upre = *reinterpret_cast<const float2*>(ubase + (size_t)(s + 1) * SC * ND + 2 * tid);
            // carry h: hhist[SC] -> hhist[0]
            if (tid < 64) {
                unsigned int v = reinterpret_cast<const unsigned int*>(hhist + SC * NH)[tid];
                reinterpret_cast<unsigned int*>(hhist)[tid] = v;
            }
            wg_barrier();
        }

        // ---- xg-compute for sub-chunk s: 16 timesteps per MFMA column-tile ----
        #pragma unroll
        for (int ct = 0; ct < 2; ++ct) {
            const int tloc = ct * 16 + cl;   // this lane's timestep column
            half8 bu = *reinterpret_cast<const half8*>(&u16[tloc * ND + q * 8]);
            floatx4 cr = rbv, cz = zbv, cn = xbv;
            cr = __builtin_amdgcn_mfma_f32_16x16x32_f16(aiR, bu, cr, 0, 0, 0);
            cz = __builtin_amdgcn_mfma_f32_16x16x32_f16(aiZ, bu, cz, 0, 0, 0);
            cn = __builtin_amdgcn_mfma_f32_16x16x32_f16(aiN, bu, cn, 0, 0, 0);
            float* xrow = &xg_lds[tloc * XGS + jb + q * 4];
            *reinterpret_cast<floatx4*>(xrow + 0 * NH) = cr;
            *reinterpret_cast<floatx4*>(xrow + 1 * NH) = cz;
            *reinterpret_cast<floatx4*>(xrow + 2 * NH) = cn;
        }
        wg_barrier();

        // ---- recurrent steps ----
        for (int tl = 0; tl < SC; ++tl) {
            // h B-fragments (same addr across 16 cl lanes -> LDS broadcast)
            const _Float16* hrow = hhist + tl * NH + q * 8;
            half8 bh0 = *reinterpret_cast<const half8*>(hrow + 0 * 32);
            half8 bh1 = *reinterpret_cast<const half8*>(hrow + 1 * 32);
            half8 bh2 = *reinterpret_cast<const half8*>(hrow + 2 * 32);
            half8 bh3 = *reinterpret_cast<const half8*>(hrow + 3 * 32);

            // xg quads as C-init (biased + prescaled)
            const float* xrow = &xg_lds[tl * XGS + jb + q * 4];
            floatx4 ra  = *reinterpret_cast<const floatx4*>(xrow + 0 * NH);
            floatx4 za  = *reinterpret_cast<const floatx4*>(xrow + 1 * NH);
            floatx4 xnv = *reinterpret_cast<const floatx4*>(xrow + 2 * NH);
            floatx4 ha  = hbv;

            // 3 independent 4-deep MFMA chains, K = 128
            ra = __builtin_amdgcn_mfma_f32_16x16x32_f16(aR[0], bh0, ra, 0, 0, 0);
            za = __builtin_amdgcn_mfma_f32_16x16x32_f16(aZ[0], bh0, za, 0, 0, 0);
            ha = __builtin_amdgcn_mfma_f32_16x16x32_f16(aN[0], bh0, ha, 0, 0, 0);
            ra = __builtin_amdgcn_mfma_f32_16x16x32_f16(aR[1], bh1, ra, 0, 0, 0);
            za = __builtin_amdgcn_mfma_f32_16x16x32_f16(aZ[1], bh1, za, 0, 0, 0);
            ha = __builtin_amdgcn_mfma_f32_16x16x32_f16(aN[1], bh1, ha, 0, 0, 0);
            ra = __builtin_amdgcn_mfma_f32_16x16x32_f16(aR[2], bh2, ra, 0, 0, 0);
            za = __builtin_amdgcn_mfma_f32_16x16x32_f16(aZ[2], bh2, za, 0, 0, 0);
            ha = __builtin_amdgcn_mfma_f32_16x16x32_f16(aN[2], bh2, ha, 0, 0, 0);
            ra = __builtin_amdgcn_mfma_f32_16x16x32_f16(aR[3], bh3, ra, 0, 0, 0);
            za = __builtin_amdgcn_mfma_f32_16x16x32_f16(aZ[3], bh3, za, 0, 0, 0);
            ha = __builtin_amdgcn_mfma_f32_16x16x32_f16(aN[3], bh3, ha, 0, 0, 0);

            // gate math: this lane handles only unit (cl&3)
            const float pre_r = sel4(ra,  s0, s1);
            const float pre_z = sel4(za,  s0, s1);
            const float pre_h = sel4(ha,  s0, s1);
            const float pre_x = sel4(xnv, s0, s1);
            const float rg = __builtin_amdgcn_rcpf(1.0f + __builtin_amdgcn_exp2f(pre_r));
            const float zg = __builtin_amdgcn_rcpf(1.0f + __builtin_amdgcn_exp2f(pre_z));
            const float ng = 1.0f - 2.0f * __builtin_amdgcn_rcpf(
                                 1.0f + __builtin_amdgcn_exp2f(pre_x + rg * pre_h));
            const float h  = ng + zg * (hold - ng);
            hold = h;

            if (cl < 4) hhist[(tl + 1) * NH + jb + q * 4 + cl] = (_Float16)h;
            wg_barrier();
        }
    }

    // final fc flush (sub-chunk NSC-1)
    if (tid < 256) {
        const int tloc = tid >> 3;
        const int part = tid & 7;
        const _Float16* hp = hhist + (tloc + 1) * NH + part * 16;
        half8 h0 = *reinterpret_cast<const half8*>(hp);
        half8 h1 = *reinterpret_cast<const half8*>(hp + 8);
        float p = 0.f;
        #pragma unroll
        for (int i = 0; i < 8; ++i) p += (float)h0[i] * fcw_lds[part * 16 + i];
        #pragma unroll
        for (int i = 0; i < 8; ++i) p += (float)h1[i] * fcw_lds[part * 16 + 8 + i];
        p += __shfl_xor(p, 1);
        p += __shfl_xor(p, 2);
        p += __shfl_xor(p, 4);
        if (part == 0) outb[(NSC - 1) * SC + tloc] = p + fcb;
    }
}

extern "C" void kernel_launch(void* const* d_in, const int* in_sizes, int n_in,
                              void* d_out, int out_size, void* d_ws, size_t ws_size,
                              hipStream_t stream)
{
    const float* u    = (const float*)d_in[0];
    const float* w_ih = (const float*)d_in[1];
    const float* w_hh = (const float*)d_in[2];
    const float* b_ih = (const float*)d_in[3];
    const float* b_hh = (const float*)d_in[4];
    const float* fc_w = (const float*)d_in[5];
    const float* fc_b = (const float*)d_in[6];

    gru_fused_kernel<<<dim3(NB), dim3(512), 0, stream>>>(
        u, w_ih, w_hh, b_ih, b_hh, fc_w, fc_b, (float*)d_out);
}